// Round 13
// baseline (668.679 us; speedup 1.0000x reference)
//
#include <hip/hip_runtime.h>

#define BB 2
#define TT 1024
#define CC 2048
#define HH 32
#define HSZ 64
#define MM (BB*TT)          // 2048 rows
#define FFND 7168
#define TM5 160
#define TDD 64
#define LCH 64
#define NCH (TT/LCH)

typedef float f32x4 __attribute__((ext_vector_type(4)));
typedef short bf16x8 __attribute__((ext_vector_type(8)));

__device__ __forceinline__ unsigned short f2bf(float f) {
    union { float f; unsigned int u; } v; v.f = f;
    return (unsigned short)((v.u + 0x7FFFu + ((v.u >> 16) & 1u)) >> 16);
}

__device__ __forceinline__ void gl_lds16(const unsigned short* g, unsigned short* l) {
    __builtin_amdgcn_global_load_lds(
        (const __attribute__((address_space(1))) unsigned int*)g,
        (__attribute__((address_space(3))) unsigned int*)l, 16, 0, 0);
}

// ---------------- fp32 -> bf16 converts ----------------
__global__ __launch_bounds__(256) void k_f2b(const float* __restrict__ in,
                                             unsigned short* __restrict__ out, int n4) {
    for (int i = blockIdx.x * 256 + threadIdx.x; i < n4; i += gridDim.x * 256) {
        float4 v = reinterpret_cast<const float4*>(in)[i];
        reinterpret_cast<ushort4*>(out)[i] =
            make_ushort4(f2bf(v.x), f2bf(v.y), f2bf(v.z), f2bf(v.w));
    }
}

__global__ __launch_bounds__(256) void k_f2b4(
        const float* __restrict__ s0, unsigned short* __restrict__ d0,
        const float* __restrict__ s1, unsigned short* __restrict__ d1,
        const float* __restrict__ s2, unsigned short* __restrict__ d2,
        const float* __restrict__ s3, unsigned short* __restrict__ d3, int n4) {
    const float* s = (blockIdx.y == 0) ? s0 : (blockIdx.y == 1) ? s1 : (blockIdx.y == 2) ? s2 : s3;
    unsigned short* d = (blockIdx.y == 0) ? d0 : (blockIdx.y == 1) ? d1 : (blockIdx.y == 2) ? d2 : d3;
    for (int i = blockIdx.x * 256 + threadIdx.x; i < n4; i += gridDim.x * 256) {
        float4 v = reinterpret_cast<const float4*>(s)[i];
        reinterpret_cast<ushort4*>(d)[i] =
            make_ushort4(f2bf(v.x), f2bf(v.y), f2bf(v.z), f2bf(v.w));
    }
}

__global__ __launch_bounds__(256) void k_f2b3(
        const float* __restrict__ s0, unsigned short* __restrict__ d0, int n0,
        const float* __restrict__ s1, unsigned short* __restrict__ d1, int n1,
        const float* __restrict__ s2, unsigned short* __restrict__ d2, int n2) {
    const float* s = (blockIdx.y == 0) ? s0 : (blockIdx.y == 1) ? s1 : s2;
    unsigned short* d = (blockIdx.y == 0) ? d0 : (blockIdx.y == 1) ? d1 : d2;
    int n4 = (blockIdx.y == 0) ? n0 : (blockIdx.y == 1) ? n1 : n2;
    for (int i = blockIdx.x * 256 + threadIdx.x; i < n4; i += gridDim.x * 256) {
        float4 v = reinterpret_cast<const float4*>(s)[i];
        reinterpret_cast<ushort4*>(d)[i] =
            make_ushort4(f2bf(v.x), f2bf(v.y), f2bf(v.z), f2bf(v.w));
    }
}

// ---------------- transpose + convert: in [K][Nsrc] fp32 -> out [Npad][K] bf16 ----
__global__ __launch_bounds__(256) void k_f2bT(const float* __restrict__ in,
        unsigned short* __restrict__ out, int K, int Nsrc, int Npad) {
    __shared__ float ts[64][65];
    const int k0 = blockIdx.x * 64, n0 = blockIdx.y * 64;
    const int tid = threadIdx.x;
#pragma unroll
    for (int q = 0; q < 16; q++) {
        int lin = tid + q * 256;
        int r = lin >> 6, c = lin & 63;
        float v = 0.f;
        if (n0 + c < Nsrc) v = in[(size_t)(k0 + r) * Nsrc + n0 + c];
        ts[r][c] = v;
    }
    __syncthreads();
#pragma unroll
    for (int q = 0; q < 16; q++) {
        int lin = tid + q * 256;
        int n = lin >> 6, k = lin & 63;
        out[(size_t)(n0 + n) * K + k0 + k] = f2bf(ts[k][n]);
    }
}

// ---------------- LayerNorm ----------------
__global__ __launch_bounds__(256) void k_ln(const float* __restrict__ x,
                                            const float* __restrict__ w,
                                            const float* __restrict__ b,
                                            float* __restrict__ out) {
    const int row = blockIdx.x;
    const float4* xr = reinterpret_cast<const float4*>(x + (size_t)row * CC);
    float4* orow = reinterpret_cast<float4*>(out + (size_t)row * CC);
    const int t = threadIdx.x;
    float4 v[2];
    float s = 0.f, s2 = 0.f;
#pragma unroll
    for (int i = 0; i < 2; i++) {
        float4 a = xr[t + i * 256];
        v[i] = a;
        s += a.x + a.y + a.z + a.w;
        s2 += a.x * a.x + a.y * a.y + a.z * a.z + a.w * a.w;
    }
#pragma unroll
    for (int o = 32; o > 0; o >>= 1) {
        s += __shfl_down(s, o, 64);
        s2 += __shfl_down(s2, o, 64);
    }
    __shared__ float ls[4], ls2[4];
    const int lane = t & 63, wv = t >> 6;
    if (lane == 0) { ls[wv] = s; ls2[wv] = s2; }
    __syncthreads();
    s = ls[0] + ls[1] + ls[2] + ls[3];
    s2 = ls2[0] + ls2[1] + ls2[2] + ls2[3];
    const float mu = s * (1.0f / CC);
    const float var = s2 * (1.0f / CC) - mu * mu;
    const float rs = rsqrtf(var + 1e-5f);
    const float4* w4 = reinterpret_cast<const float4*>(w);
    const float4* b4 = reinterpret_cast<const float4*>(b);
#pragma unroll
    for (int i = 0; i < 2; i++) {
        int c4 = t + i * 256;
        float4 wv4 = w4[c4], bv4 = b4[c4], a = v[i], o;
        o.x = (a.x - mu) * rs * wv4.x + bv4.x;
        o.y = (a.y - mu) * rs * wv4.y + bv4.y;
        o.z = (a.z - mu) * rs * wv4.z + bv4.z;
        o.w = (a.w - mu) * rs * wv4.w + bv4.w;
        orow[c4] = o;
    }
}

// ---------------- x2 = p0+p1+x ; xn = LN(x2) ----------------
__global__ __launch_bounds__(256) void k_ln_sum3(const float* __restrict__ p0,
        const float* __restrict__ p1, const float* __restrict__ x,
        const float* __restrict__ w, const float* __restrict__ b,
        float* __restrict__ x2, float* __restrict__ out) {
    const int row = blockIdx.x;
    const size_t ro = (size_t)row * (CC / 4);
    const int t = threadIdx.x;
    float4 v[2];
    float s = 0.f, s2 = 0.f;
#pragma unroll
    for (int i = 0; i < 2; i++) {
        int c4 = t + i * 256;
        float4 a = reinterpret_cast<const float4*>(p0)[ro + c4];
        float4 bq = reinterpret_cast<const float4*>(p1)[ro + c4];
        float4 c = reinterpret_cast<const float4*>(x)[ro + c4];
        float4 r;
        r.x = a.x + bq.x + c.x; r.y = a.y + bq.y + c.y;
        r.z = a.z + bq.z + c.z; r.w = a.w + bq.w + c.w;
        v[i] = r;
        reinterpret_cast<float4*>(x2)[ro + c4] = r;
        s += r.x + r.y + r.z + r.w;
        s2 += r.x * r.x + r.y * r.y + r.z * r.z + r.w * r.w;
    }
#pragma unroll
    for (int o = 32; o > 0; o >>= 1) {
        s += __shfl_down(s, o, 64);
        s2 += __shfl_down(s2, o, 64);
    }
    __shared__ float ls[4], ls2[4];
    const int lane = t & 63, wvv = t >> 6;
    if (lane == 0) { ls[wvv] = s; ls2[wvv] = s2; }
    __syncthreads();
    s = ls[0] + ls[1] + ls[2] + ls[3];
    s2 = ls2[0] + ls2[1] + ls2[2] + ls2[3];
    const float mu = s * (1.0f / CC);
    const float var = s2 * (1.0f / CC) - mu * mu;
    const float rs = rsqrtf(var + 1e-5f);
    const float4* w4 = reinterpret_cast<const float4*>(w);
    const float4* b4 = reinterpret_cast<const float4*>(b);
#pragma unroll
    for (int i = 0; i < 2; i++) {
        int c4 = t + i * 256;
        float4 wv4 = w4[c4], bv4 = b4[c4], a = v[i], o;
        o.x = (a.x - mu) * rs * wv4.x + bv4.x;
        o.y = (a.y - mu) * rs * wv4.y + bv4.y;
        o.z = (a.z - mu) * rs * wv4.z + bv4.z;
        o.w = (a.w - mu) * rs * wv4.w + bv4.w;
        reinterpret_cast<float4*>(out)[ro + c4] = o;
    }
}

// ------------- token-shift diff + bf16 mx -------------
__global__ __launch_bounds__(256) void k_buildMX(const float* __restrict__ xn,
        float* __restrict__ xx, unsigned short* __restrict__ mxb, const float* __restrict__ maax) {
    const int row = blockIdx.x;
    const int t = row % TT;
    const float4* cur = reinterpret_cast<const float4*>(xn + (size_t)row * CC);
    const float4* prev = cur - CC / 4;
    const float4* mxp = reinterpret_cast<const float4*>(maax);
#pragma unroll
    for (int i = 0; i < 2; i++) {
        int c4 = threadIdx.x + i * 256;
        float4 xc = cur[c4];
        float4 xp = (t > 0) ? prev[c4] : make_float4(0.f, 0.f, 0.f, 0.f);
        float4 ma = mxp[c4];
        float4 d;
        d.x = xp.x - xc.x; d.y = xp.y - xc.y; d.z = xp.z - xc.z; d.w = xp.w - xc.w;
        size_t id4 = (size_t)row * (CC / 4) + c4;
        reinterpret_cast<float4*>(xx)[id4] = d;
        reinterpret_cast<ushort4*>(mxb)[id4] = make_ushort4(
            f2bf(xc.x + d.x * ma.x), f2bf(xc.y + d.y * ma.y),
            f2bf(xc.z + d.z * ma.z), f2bf(xc.w + d.w * ma.w));
    }
}

// ------------- token-shift for channel mix -> bf16 kx, rx -------------
__global__ __launch_bounds__(256) void k_buildKR(const float* __restrict__ xn,
        unsigned short* __restrict__ kx, unsigned short* __restrict__ rx,
        const float* __restrict__ mk, const float* __restrict__ mr) {
    const int row = blockIdx.x;
    const int t = row % TT;
    const float4* cur = reinterpret_cast<const float4*>(xn + (size_t)row * CC);
    const float4* prev = cur - CC / 4;
#pragma unroll
    for (int i = 0; i < 2; i++) {
        int c4 = threadIdx.x + i * 256;
        float4 xc = cur[c4];
        float4 xp = (t > 0) ? prev[c4] : make_float4(0.f, 0.f, 0.f, 0.f);
        float4 mkv = reinterpret_cast<const float4*>(mk)[c4];
        float4 mrv = reinterpret_cast<const float4*>(mr)[c4];
        float4 d;
        d.x = xp.x - xc.x; d.y = xp.y - xc.y; d.z = xp.z - xc.z; d.w = xp.w - xc.w;
        size_t id4 = (size_t)row * (CC / 4) + c4;
        reinterpret_cast<ushort4*>(kx)[id4] = make_ushort4(
            f2bf(xc.x + d.x * mkv.x), f2bf(xc.y + d.y * mkv.y),
            f2bf(xc.z + d.z * mkv.z), f2bf(xc.w + d.w * mkv.w));
        reinterpret_cast<ushort4*>(rx)[id4] = make_ushort4(
            f2bf(xc.x + d.x * mrv.x), f2bf(xc.y + d.y * mrv.y),
            f2bf(xc.z + d.z * mrv.z), f2bf(xc.w + d.w * mrv.w));
    }
}

// ------------- fused P-build -------------
__global__ __launch_bounds__(256) void k_fusedP(
        const float* __restrict__ xn, const float* __restrict__ xx,
        const float* __restrict__ xxx, const float* __restrict__ w2,
        const float* __restrict__ maw, const float* __restrict__ mak,
        const float* __restrict__ mav, const float* __restrict__ mar,
        const float* __restrict__ mag,
        unsigned short* __restrict__ P0, unsigned short* __restrict__ P1,
        unsigned short* __restrict__ P2, unsigned short* __restrict__ P3,
        unsigned short* __restrict__ P4) {
    __shared__ float xs[64][33];
    __shared__ float wsh[32][68];
    const int tid = threadIdx.x;
    const int tx = tid & 15, ty = tid >> 4;
    const int m0 = blockIdx.x * 64, n0 = blockIdx.y * 64;
    float4 vxn[4], vxx[4];
#pragma unroll
    for (int i = 0; i < 4; i++) {
        size_t ro = (size_t)(m0 + ty + i * 16) * CC + n0 + tx * 4;
        vxn[i] = *reinterpret_cast<const float4*>(xn + ro);
        vxx[i] = *reinterpret_cast<const float4*>(xx + ro);
    }
    for (int f = 0; f < 5; f++) {
        __syncthreads();
#pragma unroll
        for (int q = 0; q < 2; q++) {
            int c4 = tid + q * 256;
            int rr = c4 >> 3, cj = (c4 & 7) * 4;
            *reinterpret_cast<float4*>(&xs[rr][cj]) =
                *reinterpret_cast<const float4*>(xxx + (size_t)(m0 + rr) * TM5 + f * 32 + cj);
            int kk = c4 >> 4, cn = (c4 & 15) * 4;
            *reinterpret_cast<float4*>(&wsh[kk][cn]) =
                *reinterpret_cast<const float4*>(w2 + (size_t)(f * 32 + kk) * CC + n0 + cn);
        }
        __syncthreads();
        f32x4 acc[4] = {{0,0,0,0},{0,0,0,0},{0,0,0,0},{0,0,0,0}};
#pragma unroll
        for (int kk = 0; kk < 32; kk++) {
            f32x4 wv = *reinterpret_cast<const f32x4*>(&wsh[kk][tx * 4]);
#pragma unroll
            for (int i = 0; i < 4; i++) acc[i] += xs[ty + i * 16][kk] * wv;
        }
        const float* ma = (f == 0) ? maw : (f == 1) ? mak : (f == 2) ? mav : (f == 3) ? mar : mag;
        float4 mav4 = *reinterpret_cast<const float4*>(ma + n0 + tx * 4);
        unsigned short* dst = (f == 0) ? P0 : (f == 1) ? P1 : (f == 2) ? P2 : (f == 3) ? P3 : P4;
#pragma unroll
        for (int i = 0; i < 4; i++) {
            size_t ro = (size_t)(m0 + ty + i * 16) * CC + n0 + tx * 4;
            float o0 = vxn[i].x + vxx[i].x * (mav4.x + acc[i][0]);
            float o1 = vxn[i].y + vxx[i].y * (mav4.y + acc[i][1]);
            float o2 = vxn[i].z + vxx[i].z * (mav4.z + acc[i][2]);
            float o3 = vxn[i].w + vxx[i].w * (mav4.w + acc[i][3]);
            *reinterpret_cast<ushort4*>(dst + ro) =
                make_ushort4(f2bf(o0), f2bf(o1), f2bf(o2), f2bf(o3));
        }
    }
}

// ======== descriptor for batched GEMMs ========
struct GemmDesc {
    const unsigned short* A;
    const unsigned short* W;
    float* C;
    const float* res;
    int lda, ldb, ldc, K, epi;   // 0 none,1 silu,4 sigmoid,5 +res[n]
};
struct GemmBatch { GemmDesc d[5]; };

// ======== 4-wave 128x128 GEMM core: per-wave 64x64, acc 4x4, BK=32 dbuf ========
__global__ __launch_bounds__(256, 4) void k_btb_multi(GemmBatch bt) {
    const GemmDesc gd = bt.d[blockIdx.z];
    __shared__ unsigned short As[2 * 128 * 32];
    __shared__ unsigned short Bs[2 * 128 * 32];
    const int tid = threadIdx.x;
    const int lane = tid & 63, wv = tid >> 6;
    const int nwg = gridDim.x * gridDim.y;
    const int lin = blockIdx.y * gridDim.x + blockIdx.x;
    const int cpx = nwg >> 3;
    const int swz = (lin & 7) * cpx + (lin >> 3);
    const int m0 = (swz % gridDim.x) * 128, n0 = (swz / gridDim.x) * 128;
    f32x4 acc[4][4];
#pragma unroll
    for (int i = 0; i < 4; i++)
#pragma unroll
        for (int j = 0; j < 4; j++) acc[i][j] = {0.f, 0.f, 0.f, 0.f};
    const int wm = (wv >> 1) * 64, wn = (wv & 1) * 64;
    const int frow = lane & 15, g8 = (lane >> 4) * 8;
    const unsigned ga0 = (unsigned)(m0 + (tid >> 2)) * (unsigned)gd.lda + (tid & 3) * 8;
    const unsigned ga1 = ga0 + 64u * (unsigned)gd.lda;
    const unsigned gb0 = (unsigned)(n0 + (tid >> 2)) * (unsigned)gd.ldb + (tid & 3) * 8;
    const unsigned gb1 = gb0 + 64u * (unsigned)gd.ldb;
    const int ld0 = (tid & ~63) * 8, ld1 = ((tid & ~63) + 256) * 8;

    auto stage = [&](int buf, int k0) {
        const int bo = buf * 4096;
        gl_lds16(gd.A + ga0 + k0, &As[bo + ld0]);
        gl_lds16(gd.A + ga1 + k0, &As[bo + ld1]);
        gl_lds16(gd.W + gb0 + k0, &Bs[bo + ld0]);
        gl_lds16(gd.W + gb1 + k0, &Bs[bo + ld1]);
    };
    auto compute = [&](const unsigned short* Ab, const unsigned short* Bb) {
        bf16x8 af[4], bfv[4];
#pragma unroll
        for (int i = 0; i < 4; i++)
            af[i] = *reinterpret_cast<const bf16x8*>(&Ab[(wm + i * 16 + frow) * 32 + g8]);
#pragma unroll
        for (int j = 0; j < 4; j++)
            bfv[j] = *reinterpret_cast<const bf16x8*>(&Bb[(wn + j * 16 + frow) * 32 + g8]);
#pragma unroll
        for (int i = 0; i < 4; i++)
#pragma unroll
            for (int j = 0; j < 4; j++)
                acc[i][j] = __builtin_amdgcn_mfma_f32_16x16x32_bf16(af[i], bfv[j], acc[i][j], 0, 0, 0);
    };

    stage(0, 0);
    asm volatile("s_waitcnt vmcnt(0)" ::: "memory");
    __syncthreads();
    int cur = 0;
    for (int k0 = 0; k0 < gd.K; k0 += 32) {
        const bool more = (k0 + 32) < gd.K;
        if (more) stage(cur ^ 1, k0 + 32);
        compute(&As[cur * 4096], &Bs[cur * 4096]);
        if (more) {
            asm volatile("s_waitcnt vmcnt(0)" ::: "memory");
            __syncthreads();
        }
        cur ^= 1;
    }
    const int rbase = m0 + wm + ((lane >> 4) << 2);
    const int cbase = n0 + wn + (lane & 15);
#pragma unroll
    for (int i = 0; i < 4; i++)
#pragma unroll
        for (int r4 = 0; r4 < 4; r4++) {
            int mm = rbase + i * 16 + r4;
#pragma unroll
            for (int j = 0; j < 4; j++) {
                int nn = cbase + j * 16;
                float val = acc[i][j][r4];
                size_t idx = (size_t)mm * gd.ldc + nn;
                if (gd.epi == 0) gd.C[idx] = val;
                else if (gd.epi == 1) gd.C[idx] = val / (1.f + __expf(-val));
                else if (gd.epi == 4) gd.C[idx] = 1.f / (1.f + __expf(-val));
                else if (gd.epi == 5) gd.C[idx] = val + gd.res[nn];
            }
        }
}

// ------------- single bf16 MFMA GEMM, relu^2 -> bf16 (kf) -------------
__global__ __launch_bounds__(256, 4) void k_btb_relu2(
        const unsigned short* __restrict__ A, int lda,
        const unsigned short* __restrict__ W, int ldb,
        unsigned short* __restrict__ obf, int ldc, int Kdim) {
    __shared__ unsigned short As[2 * 128 * 32];
    __shared__ unsigned short Bs[2 * 128 * 32];
    const int tid = threadIdx.x;
    const int lane = tid & 63, wv = tid >> 6;
    const int nwg = gridDim.x * gridDim.y;
    const int lin = blockIdx.y * gridDim.x + blockIdx.x;
    const int cpx = nwg >> 3;
    const int swz = (lin & 7) * cpx + (lin >> 3);
    const int m0 = (swz % gridDim.x) * 128, n0 = (swz / gridDim.x) * 128;
    f32x4 acc[4][4];
#pragma unroll
    for (int i = 0; i < 4; i++)
#pragma unroll
        for (int j = 0; j < 4; j++) acc[i][j] = {0.f, 0.f, 0.f, 0.f};
    const int wm = (wv >> 1) * 64, wn = (wv & 1) * 64;
    const int frow = lane & 15, g8 = (lane >> 4) * 8;
    const unsigned ga0 = (unsigned)(m0 + (tid >> 2)) * (unsigned)lda + (tid & 3) * 8;
    const unsigned ga1 = ga0 + 64u * (unsigned)lda;
    const unsigned gb0 = (unsigned)(n0 + (tid >> 2)) * (unsigned)ldb + (tid & 3) * 8;
    const unsigned gb1 = gb0 + 64u * (unsigned)ldb;
    const int ld0 = (tid & ~63) * 8, ld1 = ((tid & ~63) + 256) * 8;

    auto stage = [&](int buf, int k0) {
        const int bo = buf * 4096;
        gl_lds16(A + ga0 + k0, &As[bo + ld0]);
        gl_lds16(A + ga1 + k0, &As[bo + ld1]);
        gl_lds16(W + gb0 + k0, &Bs[bo + ld0]);
        gl_lds16(W + gb1 + k0, &Bs[bo + ld1]);
    };
    auto compute = [&](const unsigned short* Ab, const unsigned short* Bb) {
        bf16x8 af[4], bfv[4];
#pragma unroll
        for (int i = 0; i < 4; i++)
            af[i] = *reinterpret_cast<const bf16x8*>(&Ab[(wm + i * 16 + frow) * 32 + g8]);
#pragma unroll
        for (int j = 0; j < 4; j++)
            bfv[j] = *reinterpret_cast<const bf16x8*>(&Bb[(wn + j * 16 + frow) * 32 + g8]);
#pragma unroll
        for (int i = 0; i < 4; i++)
#pragma unroll
            for (int j = 0; j < 4; j++)
                acc[i][j] = __builtin_amdgcn_mfma_f32_16x16x32_bf16(af[i], bfv[j], acc[i][j], 0, 0, 0);
    };

    stage(0, 0);
    asm volatile("s_waitcnt vmcnt(0)" ::: "memory");
    __syncthreads();
    int cur = 0;
    for (int k0 = 0; k0 < Kdim; k0 += 32) {
        const bool more = (k0 + 32) < Kdim;
        if (more) stage(cur ^ 1, k0 + 32);
        compute(&As[cur * 4096], &Bs[cur * 4096]);
        if (more) {
            asm volatile("s_waitcnt vmcnt(0)" ::: "memory");
            __syncthreads();
        }
        cur ^= 1;
    }
    const int rbase = m0 + wm + ((lane >> 4) << 2);
    const int cbase = n0 + wn + (lane & 15);
#pragma unroll
    for (int i = 0; i < 4; i++)
#pragma unroll
        for (int r4 = 0; r4 < 4; r4++) {
            int mm = rbase + i * 16 + r4;
#pragma unroll
            for (int j = 0; j < 4; j++) {
                float t_ = fmaxf(acc[i][j][r4], 0.f);
                obf[(size_t)mm * ldc + cbase + j * 16] = f2bf(t_ * t_);
            }
        }
}

// ------------- split-K MFMA partial GEMM (XCD swizzle) -------------
__global__ __launch_bounds__(256, 4) void k_btb_sk(
        const unsigned short* __restrict__ A, int lda,
        const unsigned short* __restrict__ W, int ldb,
        float* __restrict__ P, int ldc, size_t pstride, int ksl) {
    __shared__ unsigned short As[2 * 128 * 32];
    __shared__ unsigned short Bs[2 * 128 * 32];
    const int tid = threadIdx.x;
    const int lane = tid & 63, wv = tid >> 6;
    const int nwg = gridDim.x * gridDim.y;
    const int lin = blockIdx.y * gridDim.x + blockIdx.x;
    const int cpx = nwg >> 3;
    const int swz = (lin & 7) * cpx + (lin >> 3);
    const int m0 = (swz % gridDim.x) * 128, n0 = (swz / gridDim.x) * 128;
    const int kbeg = blockIdx.z * ksl;
    f32x4 acc[4][4];
#pragma unroll
    for (int i = 0; i < 4; i++)
#pragma unroll
        for (int j = 0; j < 4; j++) acc[i][j] = {0.f, 0.f, 0.f, 0.f};
    const int wm = (wv >> 1) * 64, wn = (wv & 1) * 64;
    const int frow = lane & 15, g8 = (lane >> 4) * 8;
    const unsigned ga0 = (unsigned)(m0 + (tid >> 2)) * (unsigned)lda + (tid & 3) * 8;
    const unsigned ga1 = ga0 + 64u * (unsigned)lda;
    const unsigned gb0 = (unsigned)(n0 + (tid >> 2)) * (unsigned)ldb + (tid & 3) * 8;
    const unsigned gb1 = gb0 + 64u * (unsigned)ldb;
    const int ld0 = (tid & ~63) * 8, ld1 = ((tid & ~63) + 256) * 8;

    auto stage = [&](int buf, int k0) {
        const int bo = buf * 4096;
        gl_lds16(A + ga0 + k0, &As[bo + ld0]);
        gl_lds16(A + ga1 + k0, &As[bo + ld1]);
        gl_lds16(W + gb0 + k0, &Bs[bo + ld0]);
        gl_lds16(W + gb1 + k0, &Bs[bo + ld1]);
    };
    auto compute = [&](const unsigned short* Ab, const unsigned short* Bb) {
        bf16x8 af[4], bfv[4];
#pragma unroll
        for (int i = 0; i < 4; i++)
            af[i] = *reinterpret_cast<const bf16x8*>(&Ab[(wm + i * 16 + frow) * 32 + g8]);
#pragma unroll
        for (int j = 0; j < 4; j++)
            bfv[j] = *reinterpret_cast<const bf16x8*>(&Bb[(wn + j * 16 + frow) * 32 + g8]);
#pragma unroll
        for (int i = 0; i < 4; i++)
#pragma unroll
            for (int j = 0; j < 4; j++)
                acc[i][j] = __builtin_amdgcn_mfma_f32_16x16x32_bf16(af[i], bfv[j], acc[i][j], 0, 0, 0);
    };

    stage(0, kbeg);
    asm volatile("s_waitcnt vmcnt(0)" ::: "memory");
    __syncthreads();
    int cur = 0;
    const int kend = kbeg + ksl;
    for (int k0 = kbeg; k0 < kend; k0 += 32) {
        const bool more = (k0 + 32) < kend;
        if (more) stage(cur ^ 1, k0 + 32);
        compute(&As[cur * 4096], &Bs[cur * 4096]);
        if (more) {
            asm volatile("s_waitcnt vmcnt(0)" ::: "memory");
            __syncthreads();
        }
        cur ^= 1;
    }
    float* Cz = P + (size_t)blockIdx.z * pstride;
    const int rbase = m0 + wm + ((lane >> 4) << 2);
    const int cbase = n0 + wn + (lane & 15);
#pragma unroll
    for (int i = 0; i < 4; i++)
#pragma unroll
        for (int r4 = 0; r4 < 4; r4++) {
            int mm = rbase + i * 16 + r4;
#pragma unroll
            for (int j = 0; j < 4; j++)
                Cz[(size_t)mm * ldc + cbase + j * 16] = acc[i][j][r4];
        }
}

// ------------- reduce split-K partials + tanh. OUT: 0 fp32, 1 bf16 -------------
template<int OUT>
__global__ __launch_bounds__(256) void k_redact(const float* __restrict__ P, size_t pstride,
        void* __restrict__ out, int Nsrc, int ldp, int total) {
    int i = blockIdx.x * 256 + threadIdx.x;
    if (i >= total) return;
    int m = i / Nsrc, n = i % Nsrc;
    size_t base = (size_t)m * ldp + n;
    float s = 0.f;
#pragma unroll
    for (int z = 0; z < 8; z++) s += P[base + z * pstride];
    float v = tanhf(s);
    if constexpr (OUT == 0) ((float*)out)[i] = v;
    else ((unsigned short*)out)[i] = f2bf(v);
}

// ================== chunked WKV6 (fp32) ==================
__global__ __launch_bounds__(64) void k_wkv_prep(
        const float* __restrict__ r, const float* __restrict__ k, const float* __restrict__ w,
        float* __restrict__ Q, float* __restrict__ G, float* __restrict__ E) {
    const int blk = blockIdx.x;
    const int bh = blk >> 4, ch = blk & (NCH - 1);
    const int b = bh >> 5, h = bh & 31;
    const int i = threadIdx.x;
    float cum = 0.f;
    size_t idx = ((size_t)(b * TT + ch * LCH)) * CC + h * HSZ + i;
    for (int tau = 0; tau < LCH; tau++, idx += CC) {
        float ri = r[idx], ki = k[idx], wi = w[idx];
        Q[idx] = ri * __expf(cum);
        cum -= __expf(wi);
        G[idx] = ki * __expf(-cum);
    }
    E[(size_t)blk * HSZ + i] = __expf(cum);
}

__global__ __launch_bounds__(256) void k_sdiag(
        const float* __restrict__ r, const float* __restrict__ k,
        const float* __restrict__ u, float* __restrict__ sd) {
    const int g = blockIdx.x * 4 + (threadIdx.x >> 6);
    const int lane = threadIdx.x & 63;
    const int m = g >> 5, h = g & 31;
    const size_t idx = (size_t)m * CC + h * HSZ + lane;
    float s = r[idx] * k[idx] * u[h * HSZ + lane];
#pragma unroll
    for (int off = 32; off; off >>= 1) s += __shfl_xor(s, off, 64);
    if (lane == 0) sd[g] = s;
}

__global__ __launch_bounds__(256) void k_wkv_u(
        const float* __restrict__ G, const float* __restrict__ V,
        const float* __restrict__ E, float* __restrict__ U) {
    const int blk = blockIdx.x;
    const int bh = blk >> 4, ch = blk & (NCH - 1);
    const int b = bh >> 5, h = bh & 31;
    __shared__ float Gs[LCH][HSZ];
    __shared__ float Vs[LCH][HSZ];
    const int tid = threadIdx.x;
    const size_t rowbase = (size_t)b * TT + ch * LCH;
#pragma unroll
    for (int q = 0; q < 4; q++) {
        int c4 = tid + q * 256;
        int rr = c4 >> 4, cc = (c4 & 15) << 2;
        size_t gidx = (rowbase + rr) * CC + h * HSZ + cc;
        *(float4*)&Gs[rr][cc] = *(const float4*)&G[gidx];
        *(float4*)&Vs[rr][cc] = *(const float4*)&V[gidx];
    }
    __syncthreads();
    const int i = tid >> 2, j4 = (tid & 3) << 2;
    f32x4 a0 = {0,0,0,0}, a1 = a0, a2 = a0, a3 = a0;
    const f32x4* V4 = (const f32x4*)Vs;
#pragma unroll 8
    for (int s = 0; s < LCH; s++) {
        float gv = Gs[s][i];
        const f32x4* vr = V4 + s * 16 + j4;
        a0 += gv * vr[0]; a1 += gv * vr[1]; a2 += gv * vr[2]; a3 += gv * vr[3];
    }
    float e = E[(size_t)blk * HSZ + i];
    f32x4* o4 = (f32x4*)(U + (size_t)blk * 4096) + tid * 4;
    o4[0] = a0 * e; o4[1] = a1 * e; o4[2] = a2 * e; o4[3] = a3 * e;
}

// element-parallel scan: thread owns one (bh, e), scans 16 chunks
__global__ __launch_bounds__(256) void k_wkv_scan(
        const float* __restrict__ U, const float* __restrict__ E, float* __restrict__ S) {
    const int t = blockIdx.x * 256 + threadIdx.x;   // 64*4096 total
    const int bh = t >> 12, e = t & 4095;
    const int i = e >> 6;
    float s = 0.f;
    for (int c = 0; c < NCH; c++) {
        size_t idx = ((size_t)(bh * NCH + c) << 12) + e;
        S[idx] = s;
        if (c < NCH - 1)
            s = s * E[((size_t)(bh * NCH + c) << 6) + i] + U[idx];
    }
}

// fused att + out + groupnorm + gate -> bf16 og
__global__ __launch_bounds__(256) void k_wkv_tail(
        const float* __restrict__ Q, const float* __restrict__ G,
        const float* __restrict__ V, const float* __restrict__ S,
        const float* __restrict__ sd, const float* __restrict__ g,
        const float* __restrict__ lw, const float* __restrict__ lb,
        unsigned short* __restrict__ og) {
    const int blk = blockIdx.x;
    const int bh = blk >> 4, ch = blk & (NCH - 1);
    const int b = bh >> 5, h = bh & 31;
    __shared__ float Qs[LCH][68];
    __shared__ float Bs[LCH][68];      // G in phase1, V in phase2
    __shared__ float As_[LCH][65];
    __shared__ float Ss2[4096];
    const int tid = threadIdx.x;
    const size_t rowbase = (size_t)b * TT + ch * LCH;
#pragma unroll
    for (int q = 0; q < 4; q++) {
        int c4 = tid + q * 256;
        int rr = c4 >> 4, cc = (c4 & 15) << 2;
        size_t gidx = (rowbase + rr) * CC + h * HSZ + cc;
        *(float4*)&Qs[rr][cc] = *(const float4*)&Q[gidx];
        *(float4*)&Bs[rr][cc] = *(const float4*)&G[gidx];
    }
    __syncthreads();
    const int et = tid >> 2, s0 = tid & 3;
    {
        f32x4 qrow[16];
        const f32x4* Q4 = (const f32x4*)&Qs[et][0];
#pragma unroll
        for (int q = 0; q < 16; q++) qrow[q] = Q4[q];
#pragma unroll
        for (int ss = 0; ss < 16; ss++) {
            int sig = s0 + ss * 4;
            const f32x4* G4 = (const f32x4*)&Bs[sig][0];
            f32x4 a4 = {0, 0, 0, 0};
#pragma unroll
            for (int q = 0; q < 16; q++) a4 += qrow[q] * G4[q];
            As_[et][sig] = (sig < et) ? (a4[0] + a4[1] + a4[2] + a4[3]) : 0.f;
        }
    }
    __syncthreads();
#pragma unroll
    for (int q = 0; q < 4; q++) {
        int c4 = tid + q * 256;
        int rr = c4 >> 4, cc = (c4 & 15) << 2;
        size_t gidx = (rowbase + rr) * CC + h * HSZ + cc;
        *(float4*)&Bs[rr][cc] = *(const float4*)&V[gidx];
        *(float4*)&Ss2[c4 * 4] = *(const float4*)&S[(size_t)blk * 4096 + c4 * 4];
    }
    __syncthreads();
    const int tau = et, j4 = s0 << 2;
    f32x4 a0 = {0,0,0,0}, a1 = a0, a2 = a0, a3 = a0;
#pragma unroll 8
    for (int sg = 0; sg < LCH; sg++) {
        float a = As_[tau][sg];
        const f32x4* vr = (const f32x4*)&Bs[sg][0] + j4;
        a0 += a * vr[0]; a1 += a * vr[1]; a2 += a * vr[2]; a3 += a * vr[3];
    }
    const f32x4* S4 = (const f32x4*)Ss2;
#pragma unroll 8
    for (int i = 0; i < HSZ; i++) {
        float qv = Qs[tau][i];
        const f32x4* sr = S4 + i * 16 + j4;
        a0 += qv * sr[0]; a1 += qv * sr[1]; a2 += qv * sr[2]; a3 += qv * sr[3];
    }
    const float sv = sd[(rowbase + tau) * HH + h];
    {
        const f32x4* vr = (const f32x4*)&Bs[tau][0] + j4;
        a0 += sv * vr[0]; a1 += sv * vr[1]; a2 += sv * vr[2]; a3 += sv * vr[3];
    }
    float s = 0.f, s2 = 0.f;
#pragma unroll
    for (int q = 0; q < 4; q++) {
        f32x4 aq = (q == 0) ? a0 : (q == 1) ? a1 : (q == 2) ? a2 : a3;
#pragma unroll
        for (int w_ = 0; w_ < 4; w_++) { s += aq[w_]; s2 += aq[w_] * aq[w_]; }
    }
    s += __shfl_xor(s, 1, 64);  s2 += __shfl_xor(s2, 1, 64);
    s += __shfl_xor(s, 2, 64);  s2 += __shfl_xor(s2, 2, 64);
    const float mu = s * (1.f / 64.f);
    const float var = s2 * (1.f / 64.f) - mu * mu;
    const float rs = rsqrtf(var + 64e-5f);
    const int colbase = h * HSZ + s0 * 16;
    const size_t obase = (rowbase + tau) * CC + colbase;
#pragma unroll
    for (int q = 0; q < 4; q++) {
        f32x4 aq = (q == 0) ? a0 : (q == 1) ? a1 : (q == 2) ? a2 : a3;
        float4 lw4 = *(const float4*)(lw + colbase + q * 4);
        float4 lb4 = *(const float4*)(lb + colbase + q * 4);
        float4 g4  = *(const float4*)(g + obase + q * 4);
        ushort4 o_;
        o_.x = f2bf(((aq[0] - mu) * rs * lw4.x + lb4.x) * g4.x);
        o_.y = f2bf(((aq[1] - mu) * rs * lw4.y + lb4.y) * g4.y);
        o_.z = f2bf(((aq[2] - mu) * rs * lw4.z + lb4.z) * g4.z);
        o_.w = f2bf(((aq[3] - mu) * rs * lw4.w + lb4.w) * g4.w);
        *(ushort4*)(og + obase + q * 4) = o_;
    }
}

// ------------- final: out = x2 + rsig * kv -------------
__global__ __launch_bounds__(256) void k_final3(const float* __restrict__ x2, const float* __restrict__ rs,
        const float* __restrict__ kv, float* __restrict__ out) {
    size_t i = ((size_t)blockIdx.x * 256 + threadIdx.x) * 4;
    float4 a = *reinterpret_cast<const float4*>(x2 + i);
    float4 b = *reinterpret_cast<const float4*>(rs + i);
    float4 c = *reinterpret_cast<const float4*>(kv + i);
    float4 o;
    o.x = a.x + b.x * c.x; o.y = a.y + b.y * c.y;
    o.z = a.z + b.z * c.z; o.w = a.w + b.w * c.w;
    *reinterpret_cast<float4*>(out + i) = o;
}

extern "C" void kernel_launch(void* const* d_in, const int* in_sizes, int n_in,
                              void* d_out, int out_size, void* d_ws, size_t ws_size,
                              hipStream_t stream) {
    const float* x      = (const float*)d_in[0];
    const float* ln1_w  = (const float*)d_in[1];
    const float* ln1_b  = (const float*)d_in[2];
    const float* ln2_w  = (const float*)d_in[3];
    const float* ln2_b  = (const float*)d_in[4];
    const float* maa_x  = (const float*)d_in[5];
    const float* maa_w  = (const float*)d_in[6];
    const float* maa_k  = (const float*)d_in[7];
    const float* maa_v  = (const float*)d_in[8];
    const float* maa_r  = (const float*)d_in[9];
    const float* maa_g  = (const float*)d_in[10];
    const float* w1     = (const float*)d_in[11];
    const float* w2     = (const float*)d_in[12];
    const float* tdecay = (const float*)d_in[13];
    const float* dw1    = (const float*)d_in[14];
    const float* dw2    = (const float*)d_in[15];
    const float* faaaa  = (const float*)d_in[16];
    const float* Wr     = (const float*)d_in[17];
    const float* Wk     = (const float*)d_in[18];
    const float* Wv     = (const float*)d_in[19];
    const float* Wg     = (const float*)d_in[20];
    const float* Wo     = (const float*)d_in[21];
    const float* lnx_w  = (const float*)d_in[22];
    const float* lnx_b  = (const float*)d_in[23];
    const float* fmk    = (const float*)d_in[24];
    const float* fmr    = (const float*)d_in[25];
    const float* Wkf    = (const float*)d_in[26];
    const float* Wrf    = (const float*)d_in[27];
    const float* Wvf    = (const float*)d_in[28];
    float* out = (float*)d_out;
    (void)in_sizes; (void)n_in; (void)out_size;

    const size_t S = (size_t)MM * CC;
    const size_t need = (S * 29 / 2) * sizeof(float);
    if (ws_size < need) return;

    float* ws = (float*)d_ws;
    float* XN   = ws;                  // 0S
    float* XX   = ws + 1 * S;          // 1S: diff/G; later KXb/RXb
    float* Qq   = ws + 2 * S;          // 2S: MXb early; Q; later WRFb
    float* P0   = ws + 3 * S;          // 3S: XWb early; w; later x2
    float* Rb   = ws + 4 * S;          // 4S: r; later kv
    float* Kb   = ws + 5 * S;          // 5S: k; later rsig
    float* Vb   = ws + 6 * S;          // 6S: v; later WVFb (6..7.75)
    float* Gb   = ws + 7 * S;          // 7S: silu g
    float* Ubuf = ws + 9 * S;          // 9S: P1b/P2b early; wkv U; Wo partial0; KFb
    float* Sbuf = ws + 10 * S;         // 10S: P3b/P4b early; wkv S; Wo partial1
    float* Abuf = ws + 11 * S;         // 11S: sk partials; later WKFb (11..12.75)
    float* Gq   = XX;
    float* x2   = P0;
    unsigned short* MXb = (unsigned short*)(ws + 2 * S);
    unsigned short* XWb = (unsigned short*)(ws + 3 * S);
    unsigned short* P1b = (unsigned short*)(ws + 9 * S);
    unsigned short* P2b = (unsigned short*)(ws + 9 * S) + S;
    unsigned short* P3b = (unsigned short*)(ws + 10 * S);
    unsigned short* P4b = (unsigned short*)(ws + 10 * S) + S;
    unsigned short* OGb = (unsigned short*)(ws + 8 * S);             // 8..8.5S
    unsigned short* KXb = (unsigned short*)(ws + 1 * S);
    unsigned short* RXb = (unsigned short*)(ws + 1 * S) + S;
    unsigned short* KFb = (unsigned short*)(ws + 9 * S);             // 9..10.75S
    unsigned short* WA  = (unsigned short*)(ws + 12 * S);            // 12..14S
    unsigned short* Wrb = WA;
    unsigned short* Wkb = WA + S;
    unsigned short* Wvb = WA + 2 * S;
    unsigned short* Wgb = WA + 3 * S;
    unsigned short* WOb  = WA;                                       // 12..12.5S (post-batch1)
    unsigned short* WKFb = (unsigned short*)(ws + 11 * S);           // 11..12.75S (post-Wo-GEMM!)
    unsigned short* WVFb = (unsigned short*)(ws + 6 * S);            // 6..7.75S
    unsigned short* WRFb = (unsigned short*)(ws + 2 * S);            // 2..2.5S
    // smalls @ 14S
    float* Ebuf = ws + 14 * S;
    float* SDb  = ws + 14 * S + 65536;
    float* XXX  = ws + 14 * S + 131072;
    unsigned short* w1T  = (unsigned short*)(ws + 14 * S + 458752);
    unsigned short* dw1T = (unsigned short*)(ws + 14 * S + 720896);
    unsigned short* dw2T = (unsigned short*)(ws + 14 * S + 851968);
    unsigned short* WTb  = (unsigned short*)(ws + 14 * S + 917504);

    // ---- weight converts (tmix) ----
    k_f2b4<<<dim3(1024, 4), 256, 0, stream>>>(Wr, Wrb, Wk, Wkb, Wv, Wvb, Wg, Wgb, CC * CC / 4);
    k_f2bT<<<dim3(32, 4), 256, 0, stream>>>(w1, w1T, CC, TM5, 256);
    k_f2bT<<<dim3(32, 2), 256, 0, stream>>>(dw1, dw1T, CC, TDD, 128);
    k_f2bT<<<dim3(1, 32), 256, 0, stream>>>(dw2, dw2T, TDD, CC, CC);

    // ---- time mix ----
    k_ln<<<MM, 256, 0, stream>>>(x, ln1_w, ln1_b, XN);
    k_buildMX<<<MM, 256, 0, stream>>>(XN, XX, MXb, maa_x);
    k_btb_sk<<<dim3(16, 2, 8), 256, 0, stream>>>(MXb, CC, w1T, CC, Abuf, 256, (size_t)MM * 256, 256);
    k_redact<0><<<(MM * TM5 + 255) / 256, 256, 0, stream>>>(Abuf, (size_t)MM * 256, XXX, TM5, 256, MM * TM5);
    k_fusedP<<<dim3(MM / 64, CC / 64), 256, 0, stream>>>(XN, XX, XXX, w2,
        maa_w, maa_k, maa_v, maa_r, maa_g, XWb, P1b, P2b, P3b, P4b);
    k_btb_sk<<<dim3(16, 1, 8), 256, 0, stream>>>(XWb, CC, dw1T, CC, Abuf, 128, (size_t)MM * 128, 256);
    k_redact<1><<<(MM * TDD + 255) / 256, 256, 0, stream>>>(Abuf, (size_t)MM * 128, WTb, TDD, 128, MM * TDD);
    // ---- batched GEMMs: r, k, v, g, decay2 ----
    {
        GemmBatch b1;
        b1.d[0] = { P3b, Wrb, Rb, nullptr, CC, CC, CC, CC, 0 };
        b1.d[1] = { P1b, Wkb, Kb, nullptr, CC, CC, CC, CC, 0 };
        b1.d[2] = { P2b, Wvb, Vb, nullptr, CC, CC, CC, CC, 0 };
        b1.d[3] = { P4b, Wgb, Gb, nullptr, CC, CC, CC, CC, 1 };
        b1.d[4] = { WTb, dw2T, P0, tdecay, TDD, TDD, CC, TDD, 5 };
        k_btb_multi<<<dim3(16, 16, 5), 256, 0, stream>>>(b1);
    }
    // Wo convert only (WA free after batch1). Wkf convert waits for the Wo GEMM
    // (WKFb @11..12.75S overlaps WOb @12..12.5S) — see R10 post-mortem.
    k_f2b<<<2048, 256, 0, stream>>>(Wo, WOb, CC * CC / 4);

    // ---- chunked WKV6 ----
    k_wkv_prep<<<BB * HH * NCH, 64, 0, stream>>>(Rb, Kb, P0, Qq, Gq, Ebuf);
    k_sdiag<<<MM * HH / 4, 256, 0, stream>>>(Rb, Kb, faaaa, SDb);
    k_wkv_u<<<BB * HH * NCH, 256, 0, stream>>>(Gq, Vb, Ebuf, Ubuf);
    k_wkv_scan<<<BB * HH * 4096 / 256, 256, 0, stream>>>(Ubuf, Ebuf, Sbuf);
    k_wkv_tail<<<BB * HH * NCH, 256, 0, stream>>>(Qq, Gq, Vb, Sbuf, SDb, Gb, lnx_w, lnx_b, OGb);

    // ---- output proj (split-K z=2, partials at 9S, 10S) ----
    k_btb_sk<<<dim3(16, 16, 2), 256, 0, stream>>>(OGb, CC, WOb, CC, Ubuf, CC, S, 1024);
    k_ln_sum3<<<MM, 256, 0, stream>>>(Ubuf, Sbuf, x, ln2_w, ln2_b, x2, XN);

    // ---- channel mix ----
    k_buildKR<<<MM, 256, 0, stream>>>(XN, KXb, RXb, fmk, fmr);
    // WOb dead now -> safe to build WKFb (overlaps 12..12.5S), plus WVFb, WRFb
    k_f2b3<<<dim3(2048, 3), 256, 0, stream>>>(Wkf, WKFb, FFND * CC / 4,
                                              Wvf, WVFb, FFND * CC / 4,
                                              Wrf, WRFb, CC * CC / 4);
    k_btb_relu2<<<dim3(16, FFND / 128), 256, 0, stream>>>(KXb, CC, WKFb, CC, KFb, FFND, CC);
    // ---- batched: kv (K=7168, unsplit) + rsig = 512 blocks (2/CU) ----
    {
        GemmBatch b2;
        b2.d[0] = { KFb, WVFb, Rb, nullptr, FFND, FFND, CC, FFND, 0 };  // kv
        b2.d[1] = { RXb, WRFb, Kb, nullptr, CC,   CC,   CC, CC,   4 };  // sigmoid(r)
        b2.d[2] = b2.d[0]; b2.d[3] = b2.d[0]; b2.d[4] = b2.d[0];
        k_btb_multi<<<dim3(16, 16, 2), 256, 0, stream>>>(b2);
    }
    k_final3<<<(MM * CC / 4) / 256, 256, 0, stream>>>(x2, Kb, Rb, out);
}

// Round 14
// 610.205 us; speedup vs baseline: 1.0958x; 1.0958x over previous
//
#include <hip/hip_runtime.h>

#define BB 2
#define TT 1024
#define CC 2048
#define HH 32
#define HSZ 64
#define MM (BB*TT)          // 2048 rows
#define FFND 7168
#define TM5 160
#define TDD 64
#define LCH 64
#define NCH (TT/LCH)

typedef float f32x4 __attribute__((ext_vector_type(4)));
typedef short bf16x8 __attribute__((ext_vector_type(8)));

__device__ __forceinline__ unsigned short f2bf(float f) {
    union { float f; unsigned int u; } v; v.f = f;
    return (unsigned short)((v.u + 0x7FFFu + ((v.u >> 16) & 1u)) >> 16);
}

__device__ __forceinline__ void gl_lds16(const unsigned short* g, unsigned short* l) {
    __builtin_amdgcn_global_load_lds(
        (const __attribute__((address_space(1))) unsigned int*)g,
        (__attribute__((address_space(3))) unsigned int*)l, 16, 0, 0);
}

// ---------------- fp32 -> bf16 converts ----------------
__global__ __launch_bounds__(256) void k_f2b(const float* __restrict__ in,
                                             unsigned short* __restrict__ out, int n4) {
    for (int i = blockIdx.x * 256 + threadIdx.x; i < n4; i += gridDim.x * 256) {
        float4 v = reinterpret_cast<const float4*>(in)[i];
        reinterpret_cast<ushort4*>(out)[i] =
            make_ushort4(f2bf(v.x), f2bf(v.y), f2bf(v.z), f2bf(v.w));
    }
}

__global__ __launch_bounds__(256) void k_f2b4(
        const float* __restrict__ s0, unsigned short* __restrict__ d0,
        const float* __restrict__ s1, unsigned short* __restrict__ d1,
        const float* __restrict__ s2, unsigned short* __restrict__ d2,
        const float* __restrict__ s3, unsigned short* __restrict__ d3, int n4) {
    const float* s = (blockIdx.y == 0) ? s0 : (blockIdx.y == 1) ? s1 : (blockIdx.y == 2) ? s2 : s3;
    unsigned short* d = (blockIdx.y == 0) ? d0 : (blockIdx.y == 1) ? d1 : (blockIdx.y == 2) ? d2 : d3;
    for (int i = blockIdx.x * 256 + threadIdx.x; i < n4; i += gridDim.x * 256) {
        float4 v = reinterpret_cast<const float4*>(s)[i];
        reinterpret_cast<ushort4*>(d)[i] =
            make_ushort4(f2bf(v.x), f2bf(v.y), f2bf(v.z), f2bf(v.w));
    }
}

__global__ __launch_bounds__(256) void k_f2b3(
        const float* __restrict__ s0, unsigned short* __restrict__ d0, int n0,
        const float* __restrict__ s1, unsigned short* __restrict__ d1, int n1,
        const float* __restrict__ s2, unsigned short* __restrict__ d2, int n2) {
    const float* s = (blockIdx.y == 0) ? s0 : (blockIdx.y == 1) ? s1 : s2;
    unsigned short* d = (blockIdx.y == 0) ? d0 : (blockIdx.y == 1) ? d1 : d2;
    int n4 = (blockIdx.y == 0) ? n0 : (blockIdx.y == 1) ? n1 : n2;
    for (int i = blockIdx.x * 256 + threadIdx.x; i < n4; i += gridDim.x * 256) {
        float4 v = reinterpret_cast<const float4*>(s)[i];
        reinterpret_cast<ushort4*>(d)[i] =
            make_ushort4(f2bf(v.x), f2bf(v.y), f2bf(v.z), f2bf(v.w));
    }
}

// ---------------- transpose + convert: in [K][Nsrc] fp32 -> out [Npad][K] bf16 ----
__global__ __launch_bounds__(256) void k_f2bT(const float* __restrict__ in,
        unsigned short* __restrict__ out, int K, int Nsrc, int Npad) {
    __shared__ float ts[64][65];
    const int k0 = blockIdx.x * 64, n0 = blockIdx.y * 64;
    const int tid = threadIdx.x;
#pragma unroll
    for (int q = 0; q < 16; q++) {
        int lin = tid + q * 256;
        int r = lin >> 6, c = lin & 63;
        float v = 0.f;
        if (n0 + c < Nsrc) v = in[(size_t)(k0 + r) * Nsrc + n0 + c];
        ts[r][c] = v;
    }
    __syncthreads();
#pragma unroll
    for (int q = 0; q < 16; q++) {
        int lin = tid + q * 256;
        int n = lin >> 6, k = lin & 63;
        out[(size_t)(n0 + n) * K + k0 + k] = f2bf(ts[k][n]);
    }
}

// ---------------- LayerNorm ----------------
__global__ __launch_bounds__(256) void k_ln(const float* __restrict__ x,
                                            const float* __restrict__ w,
                                            const float* __restrict__ b,
                                            float* __restrict__ out) {
    const int row = blockIdx.x;
    const float4* xr = reinterpret_cast<const float4*>(x + (size_t)row * CC);
    float4* orow = reinterpret_cast<float4*>(out + (size_t)row * CC);
    const int t = threadIdx.x;
    float4 v[2];
    float s = 0.f, s2 = 0.f;
#pragma unroll
    for (int i = 0; i < 2; i++) {
        float4 a = xr[t + i * 256];
        v[i] = a;
        s += a.x + a.y + a.z + a.w;
        s2 += a.x * a.x + a.y * a.y + a.z * a.z + a.w * a.w;
    }
#pragma unroll
    for (int o = 32; o > 0; o >>= 1) {
        s += __shfl_down(s, o, 64);
        s2 += __shfl_down(s2, o, 64);
    }
    __shared__ float ls[4], ls2[4];
    const int lane = t & 63, wv = t >> 6;
    if (lane == 0) { ls[wv] = s; ls2[wv] = s2; }
    __syncthreads();
    s = ls[0] + ls[1] + ls[2] + ls[3];
    s2 = ls2[0] + ls2[1] + ls2[2] + ls2[3];
    const float mu = s * (1.0f / CC);
    const float var = s2 * (1.0f / CC) - mu * mu;
    const float rs = rsqrtf(var + 1e-5f);
    const float4* w4 = reinterpret_cast<const float4*>(w);
    const float4* b4 = reinterpret_cast<const float4*>(b);
#pragma unroll
    for (int i = 0; i < 2; i++) {
        int c4 = t + i * 256;
        float4 wv4 = w4[c4], bv4 = b4[c4], a = v[i], o;
        o.x = (a.x - mu) * rs * wv4.x + bv4.x;
        o.y = (a.y - mu) * rs * wv4.y + bv4.y;
        o.z = (a.z - mu) * rs * wv4.z + bv4.z;
        o.w = (a.w - mu) * rs * wv4.w + bv4.w;
        orow[c4] = o;
    }
}

// ---------------- x2 = p0+p1+x ; xn = LN(x2) ----------------
__global__ __launch_bounds__(256) void k_ln_sum3(const float* __restrict__ p0,
        const float* __restrict__ p1, const float* __restrict__ x,
        const float* __restrict__ w, const float* __restrict__ b,
        float* __restrict__ x2, float* __restrict__ out) {
    const int row = blockIdx.x;
    const size_t ro = (size_t)row * (CC / 4);
    const int t = threadIdx.x;
    float4 v[2];
    float s = 0.f, s2 = 0.f;
#pragma unroll
    for (int i = 0; i < 2; i++) {
        int c4 = t + i * 256;
        float4 a = reinterpret_cast<const float4*>(p0)[ro + c4];
        float4 bq = reinterpret_cast<const float4*>(p1)[ro + c4];
        float4 c = reinterpret_cast<const float4*>(x)[ro + c4];
        float4 r;
        r.x = a.x + bq.x + c.x; r.y = a.y + bq.y + c.y;
        r.z = a.z + bq.z + c.z; r.w = a.w + bq.w + c.w;
        v[i] = r;
        reinterpret_cast<float4*>(x2)[ro + c4] = r;
        s += r.x + r.y + r.z + r.w;
        s2 += r.x * r.x + r.y * r.y + r.z * r.z + r.w * r.w;
    }
#pragma unroll
    for (int o = 32; o > 0; o >>= 1) {
        s += __shfl_down(s, o, 64);
        s2 += __shfl_down(s2, o, 64);
    }
    __shared__ float ls[4], ls2[4];
    const int lane = t & 63, wvv = t >> 6;
    if (lane == 0) { ls[wvv] = s; ls2[wvv] = s2; }
    __syncthreads();
    s = ls[0] + ls[1] + ls[2] + ls[3];
    s2 = ls2[0] + ls2[1] + ls2[2] + ls2[3];
    const float mu = s * (1.0f / CC);
    const float var = s2 * (1.0f / CC) - mu * mu;
    const float rs = rsqrtf(var + 1e-5f);
    const float4* w4 = reinterpret_cast<const float4*>(w);
    const float4* b4 = reinterpret_cast<const float4*>(b);
#pragma unroll
    for (int i = 0; i < 2; i++) {
        int c4 = t + i * 256;
        float4 wv4 = w4[c4], bv4 = b4[c4], a = v[i], o;
        o.x = (a.x - mu) * rs * wv4.x + bv4.x;
        o.y = (a.y - mu) * rs * wv4.y + bv4.y;
        o.z = (a.z - mu) * rs * wv4.z + bv4.z;
        o.w = (a.w - mu) * rs * wv4.w + bv4.w;
        reinterpret_cast<float4*>(out)[ro + c4] = o;
    }
}

// ------------- token-shift diff + bf16 mx -------------
__global__ __launch_bounds__(256) void k_buildMX(const float* __restrict__ xn,
        float* __restrict__ xx, unsigned short* __restrict__ mxb, const float* __restrict__ maax) {
    const int row = blockIdx.x;
    const int t = row % TT;
    const float4* cur = reinterpret_cast<const float4*>(xn + (size_t)row * CC);
    const float4* prev = cur - CC / 4;
    const float4* mxp = reinterpret_cast<const float4*>(maax);
#pragma unroll
    for (int i = 0; i < 2; i++) {
        int c4 = threadIdx.x + i * 256;
        float4 xc = cur[c4];
        float4 xp = (t > 0) ? prev[c4] : make_float4(0.f, 0.f, 0.f, 0.f);
        float4 ma = mxp[c4];
        float4 d;
        d.x = xp.x - xc.x; d.y = xp.y - xc.y; d.z = xp.z - xc.z; d.w = xp.w - xc.w;
        size_t id4 = (size_t)row * (CC / 4) + c4;
        reinterpret_cast<float4*>(xx)[id4] = d;
        reinterpret_cast<ushort4*>(mxb)[id4] = make_ushort4(
            f2bf(xc.x + d.x * ma.x), f2bf(xc.y + d.y * ma.y),
            f2bf(xc.z + d.z * ma.z), f2bf(xc.w + d.w * ma.w));
    }
}

// ------------- token-shift for channel mix -> bf16 kx, rx -------------
__global__ __launch_bounds__(256) void k_buildKR(const float* __restrict__ xn,
        unsigned short* __restrict__ kx, unsigned short* __restrict__ rx,
        const float* __restrict__ mk, const float* __restrict__ mr) {
    const int row = blockIdx.x;
    const int t = row % TT;
    const float4* cur = reinterpret_cast<const float4*>(xn + (size_t)row * CC);
    const float4* prev = cur - CC / 4;
#pragma unroll
    for (int i = 0; i < 2; i++) {
        int c4 = threadIdx.x + i * 256;
        float4 xc = cur[c4];
        float4 xp = (t > 0) ? prev[c4] : make_float4(0.f, 0.f, 0.f, 0.f);
        float4 mkv = reinterpret_cast<const float4*>(mk)[c4];
        float4 mrv = reinterpret_cast<const float4*>(mr)[c4];
        float4 d;
        d.x = xp.x - xc.x; d.y = xp.y - xc.y; d.z = xp.z - xc.z; d.w = xp.w - xc.w;
        size_t id4 = (size_t)row * (CC / 4) + c4;
        reinterpret_cast<ushort4*>(kx)[id4] = make_ushort4(
            f2bf(xc.x + d.x * mkv.x), f2bf(xc.y + d.y * mkv.y),
            f2bf(xc.z + d.z * mkv.z), f2bf(xc.w + d.w * mkv.w));
        reinterpret_cast<ushort4*>(rx)[id4] = make_ushort4(
            f2bf(xc.x + d.x * mrv.x), f2bf(xc.y + d.y * mrv.y),
            f2bf(xc.z + d.z * mrv.z), f2bf(xc.w + d.w * mrv.w));
    }
}

// ------------- fused P-build -------------
__global__ __launch_bounds__(256) void k_fusedP(
        const float* __restrict__ xn, const float* __restrict__ xx,
        const float* __restrict__ xxx, const float* __restrict__ w2,
        const float* __restrict__ maw, const float* __restrict__ mak,
        const float* __restrict__ mav, const float* __restrict__ mar,
        const float* __restrict__ mag,
        unsigned short* __restrict__ P0, unsigned short* __restrict__ P1,
        unsigned short* __restrict__ P2, unsigned short* __restrict__ P3,
        unsigned short* __restrict__ P4) {
    __shared__ float xs[64][33];
    __shared__ float wsh[32][68];
    const int tid = threadIdx.x;
    const int tx = tid & 15, ty = tid >> 4;
    const int m0 = blockIdx.x * 64, n0 = blockIdx.y * 64;
    float4 vxn[4], vxx[4];
#pragma unroll
    for (int i = 0; i < 4; i++) {
        size_t ro = (size_t)(m0 + ty + i * 16) * CC + n0 + tx * 4;
        vxn[i] = *reinterpret_cast<const float4*>(xn + ro);
        vxx[i] = *reinterpret_cast<const float4*>(xx + ro);
    }
    for (int f = 0; f < 5; f++) {
        __syncthreads();
#pragma unroll
        for (int q = 0; q < 2; q++) {
            int c4 = tid + q * 256;
            int rr = c4 >> 3, cj = (c4 & 7) * 4;
            *reinterpret_cast<float4*>(&xs[rr][cj]) =
                *reinterpret_cast<const float4*>(xxx + (size_t)(m0 + rr) * TM5 + f * 32 + cj);
            int kk = c4 >> 4, cn = (c4 & 15) * 4;
            *reinterpret_cast<float4*>(&wsh[kk][cn]) =
                *reinterpret_cast<const float4*>(w2 + (size_t)(f * 32 + kk) * CC + n0 + cn);
        }
        __syncthreads();
        f32x4 acc[4] = {{0,0,0,0},{0,0,0,0},{0,0,0,0},{0,0,0,0}};
#pragma unroll
        for (int kk = 0; kk < 32; kk++) {
            f32x4 wv = *reinterpret_cast<const f32x4*>(&wsh[kk][tx * 4]);
#pragma unroll
            for (int i = 0; i < 4; i++) acc[i] += xs[ty + i * 16][kk] * wv;
        }
        const float* ma = (f == 0) ? maw : (f == 1) ? mak : (f == 2) ? mav : (f == 3) ? mar : mag;
        float4 mav4 = *reinterpret_cast<const float4*>(ma + n0 + tx * 4);
        unsigned short* dst = (f == 0) ? P0 : (f == 1) ? P1 : (f == 2) ? P2 : (f == 3) ? P3 : P4;
#pragma unroll
        for (int i = 0; i < 4; i++) {
            size_t ro = (size_t)(m0 + ty + i * 16) * CC + n0 + tx * 4;
            float o0 = vxn[i].x + vxx[i].x * (mav4.x + acc[i][0]);
            float o1 = vxn[i].y + vxx[i].y * (mav4.y + acc[i][1]);
            float o2 = vxn[i].z + vxx[i].z * (mav4.z + acc[i][2]);
            float o3 = vxn[i].w + vxx[i].w * (mav4.w + acc[i][3]);
            *reinterpret_cast<ushort4*>(dst + ro) =
                make_ushort4(f2bf(o0), f2bf(o1), f2bf(o2), f2bf(o3));
        }
    }
}

// ======== descriptor for batched GEMMs ========
struct GemmDesc {
    const unsigned short* A;
    const unsigned short* W;
    float* C;
    const float* res;
    int lda, ldb, ldc, K, epi;   // 0 none,1 silu,4 sigmoid,5 +res[n]
};
struct GemmBatch { GemmDesc d[5]; };

// ======== 4-wave 128x128 GEMM core: per-wave 64x64, acc 4x4, BK=32 dbuf ========
__global__ __launch_bounds__(256, 4) void k_btb_multi(GemmBatch bt) {
    const GemmDesc gd = bt.d[blockIdx.z];
    __shared__ unsigned short As[2 * 128 * 32];
    __shared__ unsigned short Bs[2 * 128 * 32];
    const int tid = threadIdx.x;
    const int lane = tid & 63, wv = tid >> 6;
    const int nwg = gridDim.x * gridDim.y;
    const int lin = blockIdx.y * gridDim.x + blockIdx.x;
    const int cpx = nwg >> 3;
    const int swz = (lin & 7) * cpx + (lin >> 3);
    const int m0 = (swz % gridDim.x) * 128, n0 = (swz / gridDim.x) * 128;
    f32x4 acc[4][4];
#pragma unroll
    for (int i = 0; i < 4; i++)
#pragma unroll
        for (int j = 0; j < 4; j++) acc[i][j] = {0.f, 0.f, 0.f, 0.f};
    const int wm = (wv >> 1) * 64, wn = (wv & 1) * 64;
    const int frow = lane & 15, g8 = (lane >> 4) * 8;
    const unsigned ga0 = (unsigned)(m0 + (tid >> 2)) * (unsigned)gd.lda + (tid & 3) * 8;
    const unsigned ga1 = ga0 + 64u * (unsigned)gd.lda;
    const unsigned gb0 = (unsigned)(n0 + (tid >> 2)) * (unsigned)gd.ldb + (tid & 3) * 8;
    const unsigned gb1 = gb0 + 64u * (unsigned)gd.ldb;
    const int ld0 = (tid & ~63) * 8, ld1 = ((tid & ~63) + 256) * 8;

    auto stage = [&](int buf, int k0) {
        const int bo = buf * 4096;
        gl_lds16(gd.A + ga0 + k0, &As[bo + ld0]);
        gl_lds16(gd.A + ga1 + k0, &As[bo + ld1]);
        gl_lds16(gd.W + gb0 + k0, &Bs[bo + ld0]);
        gl_lds16(gd.W + gb1 + k0, &Bs[bo + ld1]);
    };
    auto compute = [&](const unsigned short* Ab, const unsigned short* Bb) {
        bf16x8 af[4], bfv[4];
#pragma unroll
        for (int i = 0; i < 4; i++)
            af[i] = *reinterpret_cast<const bf16x8*>(&Ab[(wm + i * 16 + frow) * 32 + g8]);
#pragma unroll
        for (int j = 0; j < 4; j++)
            bfv[j] = *reinterpret_cast<const bf16x8*>(&Bb[(wn + j * 16 + frow) * 32 + g8]);
#pragma unroll
        for (int i = 0; i < 4; i++)
#pragma unroll
            for (int j = 0; j < 4; j++)
                acc[i][j] = __builtin_amdgcn_mfma_f32_16x16x32_bf16(af[i], bfv[j], acc[i][j], 0, 0, 0);
    };

    stage(0, 0);
    asm volatile("s_waitcnt vmcnt(0)" ::: "memory");
    __syncthreads();
    int cur = 0;
    for (int k0 = 0; k0 < gd.K; k0 += 32) {
        const bool more = (k0 + 32) < gd.K;
        if (more) stage(cur ^ 1, k0 + 32);
        compute(&As[cur * 4096], &Bs[cur * 4096]);
        if (more) {
            asm volatile("s_waitcnt vmcnt(0)" ::: "memory");
            __syncthreads();
        }
        cur ^= 1;
    }
    const int rbase = m0 + wm + ((lane >> 4) << 2);
    const int cbase = n0 + wn + (lane & 15);
#pragma unroll
    for (int i = 0; i < 4; i++)
#pragma unroll
        for (int r4 = 0; r4 < 4; r4++) {
            int mm = rbase + i * 16 + r4;
#pragma unroll
            for (int j = 0; j < 4; j++) {
                int nn = cbase + j * 16;
                float val = acc[i][j][r4];
                size_t idx = (size_t)mm * gd.ldc + nn;
                if (gd.epi == 0) gd.C[idx] = val;
                else if (gd.epi == 1) gd.C[idx] = val / (1.f + __expf(-val));
                else if (gd.epi == 4) gd.C[idx] = 1.f / (1.f + __expf(-val));
                else if (gd.epi == 5) gd.C[idx] = val + gd.res[nn];
            }
        }
}

// ------------- single bf16 MFMA GEMM, relu^2 -> bf16 (kf) -------------
__global__ __launch_bounds__(256, 4) void k_btb_relu2(
        const unsigned short* __restrict__ A, int lda,
        const unsigned short* __restrict__ W, int ldb,
        unsigned short* __restrict__ obf, int ldc, int Kdim) {
    __shared__ unsigned short As[2 * 128 * 32];
    __shared__ unsigned short Bs[2 * 128 * 32];
    const int tid = threadIdx.x;
    const int lane = tid & 63, wv = tid >> 6;
    const int nwg = gridDim.x * gridDim.y;
    const int lin = blockIdx.y * gridDim.x + blockIdx.x;
    const int cpx = nwg >> 3;
    const int swz = (lin & 7) * cpx + (lin >> 3);
    const int m0 = (swz % gridDim.x) * 128, n0 = (swz / gridDim.x) * 128;
    f32x4 acc[4][4];
#pragma unroll
    for (int i = 0; i < 4; i++)
#pragma unroll
        for (int j = 0; j < 4; j++) acc[i][j] = {0.f, 0.f, 0.f, 0.f};
    const int wm = (wv >> 1) * 64, wn = (wv & 1) * 64;
    const int frow = lane & 15, g8 = (lane >> 4) * 8;
    const unsigned ga0 = (unsigned)(m0 + (tid >> 2)) * (unsigned)lda + (tid & 3) * 8;
    const unsigned ga1 = ga0 + 64u * (unsigned)lda;
    const unsigned gb0 = (unsigned)(n0 + (tid >> 2)) * (unsigned)ldb + (tid & 3) * 8;
    const unsigned gb1 = gb0 + 64u * (unsigned)ldb;
    const int ld0 = (tid & ~63) * 8, ld1 = ((tid & ~63) + 256) * 8;

    auto stage = [&](int buf, int k0) {
        const int bo = buf * 4096;
        gl_lds16(A + ga0 + k0, &As[bo + ld0]);
        gl_lds16(A + ga1 + k0, &As[bo + ld1]);
        gl_lds16(W + gb0 + k0, &Bs[bo + ld0]);
        gl_lds16(W + gb1 + k0, &Bs[bo + ld1]);
    };
    auto compute = [&](const unsigned short* Ab, const unsigned short* Bb) {
        bf16x8 af[4], bfv[4];
#pragma unroll
        for (int i = 0; i < 4; i++)
            af[i] = *reinterpret_cast<const bf16x8*>(&Ab[(wm + i * 16 + frow) * 32 + g8]);
#pragma unroll
        for (int j = 0; j < 4; j++)
            bfv[j] = *reinterpret_cast<const bf16x8*>(&Bb[(wn + j * 16 + frow) * 32 + g8]);
#pragma unroll
        for (int i = 0; i < 4; i++)
#pragma unroll
            for (int j = 0; j < 4; j++)
                acc[i][j] = __builtin_amdgcn_mfma_f32_16x16x32_bf16(af[i], bfv[j], acc[i][j], 0, 0, 0);
    };

    stage(0, 0);
    asm volatile("s_waitcnt vmcnt(0)" ::: "memory");
    __syncthreads();
    int cur = 0;
    for (int k0 = 0; k0 < Kdim; k0 += 32) {
        const bool more = (k0 + 32) < Kdim;
        if (more) stage(cur ^ 1, k0 + 32);
        compute(&As[cur * 4096], &Bs[cur * 4096]);
        if (more) {
            asm volatile("s_waitcnt vmcnt(0)" ::: "memory");
            __syncthreads();
        }
        cur ^= 1;
    }
    const int rbase = m0 + wm + ((lane >> 4) << 2);
    const int cbase = n0 + wn + (lane & 15);
#pragma unroll
    for (int i = 0; i < 4; i++)
#pragma unroll
        for (int r4 = 0; r4 < 4; r4++) {
            int mm = rbase + i * 16 + r4;
#pragma unroll
            for (int j = 0; j < 4; j++) {
                float t_ = fmaxf(acc[i][j][r4], 0.f);
                obf[(size_t)mm * ldc + cbase + j * 16] = f2bf(t_ * t_);
            }
        }
}

// ------------- split-K MFMA partial GEMM (XCD swizzle) -------------
__global__ __launch_bounds__(256, 4) void k_btb_sk(
        const unsigned short* __restrict__ A, int lda,
        const unsigned short* __restrict__ W, int ldb,
        float* __restrict__ P, int ldc, size_t pstride, int ksl) {
    __shared__ unsigned short As[2 * 128 * 32];
    __shared__ unsigned short Bs[2 * 128 * 32];
    const int tid = threadIdx.x;
    const int lane = tid & 63, wv = tid >> 6;
    const int nwg = gridDim.x * gridDim.y;
    const int lin = blockIdx.y * gridDim.x + blockIdx.x;
    const int cpx = nwg >> 3;
    const int swz = (lin & 7) * cpx + (lin >> 3);
    const int m0 = (swz % gridDim.x) * 128, n0 = (swz / gridDim.x) * 128;
    const int kbeg = blockIdx.z * ksl;
    f32x4 acc[4][4];
#pragma unroll
    for (int i = 0; i < 4; i++)
#pragma unroll
        for (int j = 0; j < 4; j++) acc[i][j] = {0.f, 0.f, 0.f, 0.f};
    const int wm = (wv >> 1) * 64, wn = (wv & 1) * 64;
    const int frow = lane & 15, g8 = (lane >> 4) * 8;
    const unsigned ga0 = (unsigned)(m0 + (tid >> 2)) * (unsigned)lda + (tid & 3) * 8;
    const unsigned ga1 = ga0 + 64u * (unsigned)lda;
    const unsigned gb0 = (unsigned)(n0 + (tid >> 2)) * (unsigned)ldb + (tid & 3) * 8;
    const unsigned gb1 = gb0 + 64u * (unsigned)ldb;
    const int ld0 = (tid & ~63) * 8, ld1 = ((tid & ~63) + 256) * 8;

    auto stage = [&](int buf, int k0) {
        const int bo = buf * 4096;
        gl_lds16(A + ga0 + k0, &As[bo + ld0]);
        gl_lds16(A + ga1 + k0, &As[bo + ld1]);
        gl_lds16(W + gb0 + k0, &Bs[bo + ld0]);
        gl_lds16(W + gb1 + k0, &Bs[bo + ld1]);
    };
    auto compute = [&](const unsigned short* Ab, const unsigned short* Bb) {
        bf16x8 af[4], bfv[4];
#pragma unroll
        for (int i = 0; i < 4; i++)
            af[i] = *reinterpret_cast<const bf16x8*>(&Ab[(wm + i * 16 + frow) * 32 + g8]);
#pragma unroll
        for (int j = 0; j < 4; j++)
            bfv[j] = *reinterpret_cast<const bf16x8*>(&Bb[(wn + j * 16 + frow) * 32 + g8]);
#pragma unroll
        for (int i = 0; i < 4; i++)
#pragma unroll
            for (int j = 0; j < 4; j++)
                acc[i][j] = __builtin_amdgcn_mfma_f32_16x16x32_bf16(af[i], bfv[j], acc[i][j], 0, 0, 0);
    };

    stage(0, kbeg);
    asm volatile("s_waitcnt vmcnt(0)" ::: "memory");
    __syncthreads();
    int cur = 0;
    const int kend = kbeg + ksl;
    for (int k0 = kbeg; k0 < kend; k0 += 32) {
        const bool more = (k0 + 32) < kend;
        if (more) stage(cur ^ 1, k0 + 32);
        compute(&As[cur * 4096], &Bs[cur * 4096]);
        if (more) {
            asm volatile("s_waitcnt vmcnt(0)" ::: "memory");
            __syncthreads();
        }
        cur ^= 1;
    }
    float* Cz = P + (size_t)blockIdx.z * pstride;
    const int rbase = m0 + wm + ((lane >> 4) << 2);
    const int cbase = n0 + wn + (lane & 15);
#pragma unroll
    for (int i = 0; i < 4; i++)
#pragma unroll
        for (int r4 = 0; r4 < 4; r4++) {
            int mm = rbase + i * 16 + r4;
#pragma unroll
            for (int j = 0; j < 4; j++)
                Cz[(size_t)mm * ldc + cbase + j * 16] = acc[i][j][r4];
        }
}

// ------------- reduce split-K partials + tanh. OUT: 0 fp32, 1 bf16 -------------
template<int OUT>
__global__ __launch_bounds__(256) void k_redact(const float* __restrict__ P, size_t pstride,
        void* __restrict__ out, int Nsrc, int ldp, int total) {
    int i = blockIdx.x * 256 + threadIdx.x;
    if (i >= total) return;
    int m = i / Nsrc, n = i % Nsrc;
    size_t base = (size_t)m * ldp + n;
    float s = 0.f;
#pragma unroll
    for (int z = 0; z < 8; z++) s += P[base + z * pstride];
    float v = tanhf(s);
    if constexpr (OUT == 0) ((float*)out)[i] = v;
    else ((unsigned short*)out)[i] = f2bf(v);
}

// ================== chunked WKV6 (fp32) ==================
__global__ __launch_bounds__(64) void k_wkv_prep(
        const float* __restrict__ r, const float* __restrict__ k, const float* __restrict__ w,
        float* __restrict__ Q, float* __restrict__ G, float* __restrict__ E) {
    const int blk = blockIdx.x;
    const int bh = blk >> 4, ch = blk & (NCH - 1);
    const int b = bh >> 5, h = bh & 31;
    const int i = threadIdx.x;
    float cum = 0.f;
    size_t idx = ((size_t)(b * TT + ch * LCH)) * CC + h * HSZ + i;
    for (int tau = 0; tau < LCH; tau++, idx += CC) {
        float ri = r[idx], ki = k[idx], wi = w[idx];
        Q[idx] = ri * __expf(cum);
        cum -= __expf(wi);
        G[idx] = ki * __expf(-cum);
    }
    E[(size_t)blk * HSZ + i] = __expf(cum);
}

__global__ __launch_bounds__(256) void k_sdiag(
        const float* __restrict__ r, const float* __restrict__ k,
        const float* __restrict__ u, float* __restrict__ sd) {
    const int g = blockIdx.x * 4 + (threadIdx.x >> 6);
    const int lane = threadIdx.x & 63;
    const int m = g >> 5, h = g & 31;
    const size_t idx = (size_t)m * CC + h * HSZ + lane;
    float s = r[idx] * k[idx] * u[h * HSZ + lane];
#pragma unroll
    for (int off = 32; off; off >>= 1) s += __shfl_xor(s, off, 64);
    if (lane == 0) sd[g] = s;
}

__global__ __launch_bounds__(256) void k_wkv_u(
        const float* __restrict__ G, const float* __restrict__ V,
        const float* __restrict__ E, float* __restrict__ U) {
    const int blk = blockIdx.x;
    const int bh = blk >> 4, ch = blk & (NCH - 1);
    const int b = bh >> 5, h = bh & 31;
    __shared__ float Gs[LCH][HSZ];
    __shared__ float Vs[LCH][HSZ];
    const int tid = threadIdx.x;
    const size_t rowbase = (size_t)b * TT + ch * LCH;
#pragma unroll
    for (int q = 0; q < 4; q++) {
        int c4 = tid + q * 256;
        int rr = c4 >> 4, cc = (c4 & 15) << 2;
        size_t gidx = (rowbase + rr) * CC + h * HSZ + cc;
        *(float4*)&Gs[rr][cc] = *(const float4*)&G[gidx];
        *(float4*)&Vs[rr][cc] = *(const float4*)&V[gidx];
    }
    __syncthreads();
    const int i = tid >> 2, j4 = (tid & 3) << 2;
    f32x4 a0 = {0,0,0,0}, a1 = a0, a2 = a0, a3 = a0;
    const f32x4* V4 = (const f32x4*)Vs;
#pragma unroll 8
    for (int s = 0; s < LCH; s++) {
        float gv = Gs[s][i];
        const f32x4* vr = V4 + s * 16 + j4;
        a0 += gv * vr[0]; a1 += gv * vr[1]; a2 += gv * vr[2]; a3 += gv * vr[3];
    }
    float e = E[(size_t)blk * HSZ + i];
    f32x4* o4 = (f32x4*)(U + (size_t)blk * 4096) + tid * 4;
    o4[0] = a0 * e; o4[1] = a1 * e; o4[2] = a2 * e; o4[3] = a3 * e;
}

// element-parallel scan: thread owns one (bh, e), scans 16 chunks
__global__ __launch_bounds__(256) void k_wkv_scan(
        const float* __restrict__ U, const float* __restrict__ E, float* __restrict__ S) {
    const int t = blockIdx.x * 256 + threadIdx.x;   // 64*4096 total
    const int bh = t >> 12, e = t & 4095;
    const int i = e >> 6;
    float s = 0.f;
    for (int c = 0; c < NCH; c++) {
        size_t idx = ((size_t)(bh * NCH + c) << 12) + e;
        S[idx] = s;
        if (c < NCH - 1)
            s = s * E[((size_t)(bh * NCH + c) << 6) + i] + U[idx];
    }
}

// fused att + out + groupnorm + gate -> bf16 og
__global__ __launch_bounds__(256) void k_wkv_tail(
        const float* __restrict__ Q, const float* __restrict__ G,
        const float* __restrict__ V, const float* __restrict__ S,
        const float* __restrict__ sd, const float* __restrict__ g,
        const float* __restrict__ lw, const float* __restrict__ lb,
        unsigned short* __restrict__ og) {
    const int blk = blockIdx.x;
    const int bh = blk >> 4, ch = blk & (NCH - 1);
    const int b = bh >> 5, h = bh & 31;
    __shared__ float Qs[LCH][68];
    __shared__ float Bs[LCH][68];      // G in phase1, V in phase2
    __shared__ float As_[LCH][65];
    __shared__ float Ss2[4096];
    const int tid = threadIdx.x;
    const size_t rowbase = (size_t)b * TT + ch * LCH;
#pragma unroll
    for (int q = 0; q < 4; q++) {
        int c4 = tid + q * 256;
        int rr = c4 >> 4, cc = (c4 & 15) << 2;
        size_t gidx = (rowbase + rr) * CC + h * HSZ + cc;
        *(float4*)&Qs[rr][cc] = *(const float4*)&Q[gidx];
        *(float4*)&Bs[rr][cc] = *(const float4*)&G[gidx];
    }
    __syncthreads();
    const int et = tid >> 2, s0 = tid & 3;
    {
        f32x4 qrow[16];
        const f32x4* Q4 = (const f32x4*)&Qs[et][0];
#pragma unroll
        for (int q = 0; q < 16; q++) qrow[q] = Q4[q];
#pragma unroll
        for (int ss = 0; ss < 16; ss++) {
            int sig = s0 + ss * 4;
            const f32x4* G4 = (const f32x4*)&Bs[sig][0];
            f32x4 a4 = {0, 0, 0, 0};
#pragma unroll
            for (int q = 0; q < 16; q++) a4 += qrow[q] * G4[q];
            As_[et][sig] = (sig < et) ? (a4[0] + a4[1] + a4[2] + a4[3]) : 0.f;
        }
    }
    __syncthreads();
#pragma unroll
    for (int q = 0; q < 4; q++) {
        int c4 = tid + q * 256;
        int rr = c4 >> 4, cc = (c4 & 15) << 2;
        size_t gidx = (rowbase + rr) * CC + h * HSZ + cc;
        *(float4*)&Bs[rr][cc] = *(const float4*)&V[gidx];
        *(float4*)&Ss2[c4 * 4] = *(const float4*)&S[(size_t)blk * 4096 + c4 * 4];
    }
    __syncthreads();
    const int tau = et, j4 = s0 << 2;
    f32x4 a0 = {0,0,0,0}, a1 = a0, a2 = a0, a3 = a0;
#pragma unroll 8
    for (int sg = 0; sg < LCH; sg++) {
        float a = As_[tau][sg];
        const f32x4* vr = (const f32x4*)&Bs[sg][0] + j4;
        a0 += a * vr[0]; a1 += a * vr[1]; a2 += a * vr[2]; a3 += a * vr[3];
    }
    const f32x4* S4 = (const f32x4*)Ss2;
#pragma unroll 8
    for (int i = 0; i < HSZ; i++) {
        float qv = Qs[tau][i];
        const f32x4* sr = S4 + i * 16 + j4;
        a0 += qv * sr[0]; a1 += qv * sr[1]; a2 += qv * sr[2]; a3 += qv * sr[3];
    }
    const float sv = sd[(rowbase + tau) * HH + h];
    {
        const f32x4* vr = (const f32x4*)&Bs[tau][0] + j4;
        a0 += sv * vr[0]; a1 += sv * vr[1]; a2 += sv * vr[2]; a3 += sv * vr[3];
    }
    float s = 0.f, s2 = 0.f;
#pragma unroll
    for (int q = 0; q < 4; q++) {
        f32x4 aq = (q == 0) ? a0 : (q == 1) ? a1 : (q == 2) ? a2 : a3;
#pragma unroll
        for (int w_ = 0; w_ < 4; w_++) { s += aq[w_]; s2 += aq[w_] * aq[w_]; }
    }
    s += __shfl_xor(s, 1, 64);  s2 += __shfl_xor(s2, 1, 64);
    s += __shfl_xor(s, 2, 64);  s2 += __shfl_xor(s2, 2, 64);
    const float mu = s * (1.f / 64.f);
    const float var = s2 * (1.f / 64.f) - mu * mu;
    const float rs = rsqrtf(var + 64e-5f);
    const int colbase = h * HSZ + s0 * 16;
    const size_t obase = (rowbase + tau) * CC + colbase;
#pragma unroll
    for (int q = 0; q < 4; q++) {
        f32x4 aq = (q == 0) ? a0 : (q == 1) ? a1 : (q == 2) ? a2 : a3;
        float4 lw4 = *(const float4*)(lw + colbase + q * 4);
        float4 lb4 = *(const float4*)(lb + colbase + q * 4);
        float4 g4  = *(const float4*)(g + obase + q * 4);
        ushort4 o_;
        o_.x = f2bf(((aq[0] - mu) * rs * lw4.x + lb4.x) * g4.x);
        o_.y = f2bf(((aq[1] - mu) * rs * lw4.y + lb4.y) * g4.y);
        o_.z = f2bf(((aq[2] - mu) * rs * lw4.z + lb4.z) * g4.z);
        o_.w = f2bf(((aq[3] - mu) * rs * lw4.w + lb4.w) * g4.w);
        *(ushort4*)(og + obase + q * 4) = o_;
    }
}

// ------------- final: out = x2 + rsig * (kvP0 + kvP1) -------------
__global__ __launch_bounds__(256) void k_final2(const float* __restrict__ x2, const float* __restrict__ rs,
        const float* __restrict__ p0, const float* __restrict__ p1, float* __restrict__ out) {
    size_t i = ((size_t)blockIdx.x * 256 + threadIdx.x) * 4;
    float4 a = *reinterpret_cast<const float4*>(x2 + i);
    float4 b = *reinterpret_cast<const float4*>(rs + i);
    float4 c = *reinterpret_cast<const float4*>(p0 + i);
    float4 d = *reinterpret_cast<const float4*>(p1 + i);
    float4 o;
    o.x = a.x + b.x * (c.x + d.x); o.y = a.y + b.y * (c.y + d.y);
    o.z = a.z + b.z * (c.z + d.z); o.w = a.w + b.w * (c.w + d.w);
    *reinterpret_cast<float4*>(out + i) = o;
}

extern "C" void kernel_launch(void* const* d_in, const int* in_sizes, int n_in,
                              void* d_out, int out_size, void* d_ws, size_t ws_size,
                              hipStream_t stream) {
    const float* x      = (const float*)d_in[0];
    const float* ln1_w  = (const float*)d_in[1];
    const float* ln1_b  = (const float*)d_in[2];
    const float* ln2_w  = (const float*)d_in[3];
    const float* ln2_b  = (const float*)d_in[4];
    const float* maa_x  = (const float*)d_in[5];
    const float* maa_w  = (const float*)d_in[6];
    const float* maa_k  = (const float*)d_in[7];
    const float* maa_v  = (const float*)d_in[8];
    const float* maa_r  = (const float*)d_in[9];
    const float* maa_g  = (const float*)d_in[10];
    const float* w1     = (const float*)d_in[11];
    const float* w2     = (const float*)d_in[12];
    const float* tdecay = (const float*)d_in[13];
    const float* dw1    = (const float*)d_in[14];
    const float* dw2    = (const float*)d_in[15];
    const float* faaaa  = (const float*)d_in[16];
    const float* Wr     = (const float*)d_in[17];
    const float* Wk     = (const float*)d_in[18];
    const float* Wv     = (const float*)d_in[19];
    const float* Wg     = (const float*)d_in[20];
    const float* Wo     = (const float*)d_in[21];
    const float* lnx_w  = (const float*)d_in[22];
    const float* lnx_b  = (const float*)d_in[23];
    const float* fmk    = (const float*)d_in[24];
    const float* fmr    = (const float*)d_in[25];
    const float* Wkf    = (const float*)d_in[26];
    const float* Wrf    = (const float*)d_in[27];
    const float* Wvf    = (const float*)d_in[28];
    float* out = (float*)d_out;
    (void)in_sizes; (void)n_in; (void)out_size;

    const size_t S = (size_t)MM * CC;
    const size_t need = (S * 29 / 2) * sizeof(float);
    if (ws_size < need) return;

    float* ws = (float*)d_ws;
    float* XN   = ws;                  // 0S
    float* XX   = ws + 1 * S;          // 1S: diff/G; later KXb/RXb
    float* Qq   = ws + 2 * S;          // 2S: MXb early; Q; later WRFb
    float* P0   = ws + 3 * S;          // 3S: XWb early; w; later x2
    float* Rb   = ws + 4 * S;          // 4S: r; later kv partial0
    float* Kb   = ws + 5 * S;          // 5S: k; later rsig
    float* Vb   = ws + 6 * S;          // 6S: v; later WVFb (6..7.75)
    float* Gb   = ws + 7 * S;          // 7S: silu g
    float* Ubuf = ws + 9 * S;          // 9S: P1b/P2b early; wkv U; Wo partial0; KFb
    float* Sbuf = ws + 10 * S;         // 10S: P3b/P4b early; wkv S; Wo partial1
    float* Abuf = ws + 11 * S;         // 11S: sk partials; later WKFb (11..12.75)
    float* Gq   = XX;
    float* x2   = P0;
    unsigned short* MXb = (unsigned short*)(ws + 2 * S);
    unsigned short* XWb = (unsigned short*)(ws + 3 * S);
    unsigned short* P1b = (unsigned short*)(ws + 9 * S);
    unsigned short* P2b = (unsigned short*)(ws + 9 * S) + S;
    unsigned short* P3b = (unsigned short*)(ws + 10 * S);
    unsigned short* P4b = (unsigned short*)(ws + 10 * S) + S;
    unsigned short* OGb = (unsigned short*)(ws + 8 * S);             // 8..8.5S
    unsigned short* KXb = (unsigned short*)(ws + 1 * S);
    unsigned short* RXb = (unsigned short*)(ws + 1 * S) + S;
    unsigned short* KFb = (unsigned short*)(ws + 9 * S);             // 9..10.75S
    unsigned short* WA  = (unsigned short*)(ws + 12 * S);            // 12..14S
    unsigned short* Wrb = WA;
    unsigned short* Wkb = WA + S;
    unsigned short* Wvb = WA + 2 * S;
    unsigned short* Wgb = WA + 3 * S;
    unsigned short* WOb  = WA;                                       // 12..12.5S (post-batch1)
    unsigned short* WKFb = (unsigned short*)(ws + 11 * S);           // 11..12.75S (post-Wo-GEMM!)
    unsigned short* WVFb = (unsigned short*)(ws + 6 * S);            // 6..7.75S
    unsigned short* WRFb = (unsigned short*)(ws + 2 * S);            // 2..2.5S
    // smalls @ 14S
    float* Ebuf = ws + 14 * S;
    float* SDb  = ws + 14 * S + 65536;
    float* XXX  = ws + 14 * S + 131072;
    unsigned short* w1T  = (unsigned short*)(ws + 14 * S + 458752);
    unsigned short* dw1T = (unsigned short*)(ws + 14 * S + 720896);
    unsigned short* dw2T = (unsigned short*)(ws + 14 * S + 851968);
    unsigned short* WTb  = (unsigned short*)(ws + 14 * S + 917504);

    // ---- weight converts (tmix) ----
    k_f2b4<<<dim3(1024, 4), 256, 0, stream>>>(Wr, Wrb, Wk, Wkb, Wv, Wvb, Wg, Wgb, CC * CC / 4);
    k_f2bT<<<dim3(32, 4), 256, 0, stream>>>(w1, w1T, CC, TM5, 256);
    k_f2bT<<<dim3(32, 2), 256, 0, stream>>>(dw1, dw1T, CC, TDD, 128);
    k_f2bT<<<dim3(1, 32), 256, 0, stream>>>(dw2, dw2T, TDD, CC, CC);

    // ---- time mix ----
    k_ln<<<MM, 256, 0, stream>>>(x, ln1_w, ln1_b, XN);
    k_buildMX<<<MM, 256, 0, stream>>>(XN, XX, MXb, maa_x);
    k_btb_sk<<<dim3(16, 2, 8), 256, 0, stream>>>(MXb, CC, w1T, CC, Abuf, 256, (size_t)MM * 256, 256);
    k_redact<0><<<(MM * TM5 + 255) / 256, 256, 0, stream>>>(Abuf, (size_t)MM * 256, XXX, TM5, 256, MM * TM5);
    k_fusedP<<<dim3(MM / 64, CC / 64), 256, 0, stream>>>(XN, XX, XXX, w2,
        maa_w, maa_k, maa_v, maa_r, maa_g, XWb, P1b, P2b, P3b, P4b);
    k_btb_sk<<<dim3(16, 1, 8), 256, 0, stream>>>(XWb, CC, dw1T, CC, Abuf, 128, (size_t)MM * 128, 256);
    k_redact<1><<<(MM * TDD + 255) / 256, 256, 0, stream>>>(Abuf, (size_t)MM * 128, WTb, TDD, 128, MM * TDD);
    // ---- batched GEMMs: r, k, v, g, decay2 ----
    {
        GemmBatch b1;
        b1.d[0] = { P3b, Wrb, Rb, nullptr, CC, CC, CC, CC, 0 };
        b1.d[1] = { P1b, Wkb, Kb, nullptr, CC, CC, CC, CC, 0 };
        b1.d[2] = { P2b, Wvb, Vb, nullptr, CC, CC, CC, CC, 0 };
        b1.d[3] = { P4b, Wgb, Gb, nullptr, CC, CC, CC, CC, 1 };
        b1.d[4] = { WTb, dw2T, P0, tdecay, TDD, TDD, CC, TDD, 5 };
        k_btb_multi<<<dim3(16, 16, 5), 256, 0, stream>>>(b1);
    }
    // Wo convert only (WA free after batch1). Wkf convert waits for the Wo GEMM
    // (WKFb @11..12.75S overlaps WOb @12..12.5S) — see R10 post-mortem.
    k_f2b<<<2048, 256, 0, stream>>>(Wo, WOb, CC * CC / 4);

    // ---- chunked WKV6 ----
    k_wkv_prep<<<BB * HH * NCH, 64, 0, stream>>>(Rb, Kb, P0, Qq, Gq, Ebuf);
    k_sdiag<<<MM * HH / 4, 256, 0, stream>>>(Rb, Kb, faaaa, SDb);
    k_wkv_u<<<BB * HH * NCH, 256, 0, stream>>>(Gq, Vb, Ebuf, Ubuf);
    k_wkv_scan<<<BB * HH * 4096 / 256, 256, 0, stream>>>(Ubuf, Ebuf, Sbuf);
    k_wkv_tail<<<BB * HH * NCH, 256, 0, stream>>>(Qq, Gq, Vb, Sbuf, SDb, Gb, lnx_w, lnx_b, OGb);

    // ---- output proj (split-K z=2, partials at 9S, 10S) ----
    k_btb_sk<<<dim3(16, 16, 2), 256, 0, stream>>>(OGb, CC, WOb, CC, Ubuf, CC, S, 1024);
    k_ln_sum3<<<MM, 256, 0, stream>>>(Ubuf, Sbuf, x, ln2_w, ln2_b, x2, XN);

    // ---- channel mix ----
    k_buildKR<<<MM, 256, 0, stream>>>(XN, KXb, RXb, fmk, fmr);
    // WOb dead now -> safe to build WKFb (overlaps 12..12.5S), plus WVFb, WRFb
    k_f2b3<<<dim3(2048, 3), 256, 0, stream>>>(Wkf, WKFb, FFND * CC / 4,
                                              Wvf, WVFb, FFND * CC / 4,
                                              Wrf, WRFb, CC * CC / 4);
    k_btb_relu2<<<dim3(16, FFND / 128), 256, 0, stream>>>(KXb, CC, WKFb, CC, KFb, FFND, CC);
    {
        GemmBatch b2;
        b2.d[0] = { KFb,        WVFb,        Rb,          nullptr, FFND, FFND, CC, FFND / 2, 0 };
        b2.d[1] = { KFb + 3584, WVFb + 3584, ws + 8 * S,  nullptr, FFND, FFND, CC, FFND / 2, 0 };
        b2.d[2] = { RXb, WRFb, Kb, nullptr, CC, CC, CC, CC, 4 };
        b2.d[3] = b2.d[0]; b2.d[4] = b2.d[0];
        k_btb_multi<<<dim3(16, 16, 3), 256, 0, stream>>>(b2);
    }
    k_final2<<<(MM * CC / 4) / 256, 256, 0, stream>>>(x2, Kb, Rb, ws + 8 * S, out);
}